// Round 10
// baseline (10561.179 us; speedup 1.0000x reference)
//
#include <hip/hip_runtime.h>

#pragma clang fp contract(off)

#define NPT 32768
#define NKP 4096
#define GX 40
#define GY 20
#define GZ 4
#define NCELL_PAD 4096

// ============================ FPS =================================
// Chunk-batched bbox-pruned FPS (validated round 9: 7.4ms, bit-exact).
// Round-9 counters: SQ_LDS_BANK_CONFLICT=2.68M/dispatch = 32 lanes
// atomicMax'ing the same u64 ckey address (~0.65us/iter serialization).
// Fix: each needy chunk is processed by one 32-lane half exactly once per
// iter, so NO atomic needed -- 5-step in-half __shfl_xor f64-fmax reduce
// (positive doubles: fmax == u64 lex max, tie-exact) + one plain ds_write
// by lane jj==0. Owner re-reads ckey[t] after the pass loop (same-wave DS
// program order). Reset step eliminated (plain store overwrites).
#define FPS_T 1024
#define PPT 32

__global__ __attribute__((amdgpu_flat_work_group_size(FPS_T, FPS_T)))
__attribute__((amdgpu_waves_per_eu(4, 4))) void k_fps(
    const float* __restrict__ xyz, const float4* __restrict__ rxyz,
    int* __restrict__ kp) {
#pragma clang fp contract(off)
    __shared__ float mdl[NPT];                 // 128 KiB min-dist, sorted order
    __shared__ unsigned long long ckey[1024];  // per-chunk packed (maxmd, ~oid)
    __shared__ unsigned long long gbest[2];    // parity global-argmax slots
    const int t = threadIdx.x;
    const int lane = t & 63;
    const int w = t >> 6;

    for (int i = t; i < NPT; i += FPS_T) mdl[i] = 1e10f;
    ckey[t] = 0ULL;
    if (t == 0) { gbest[0] = 0ULL; gbest[1] = 0ULL; kp[0] = 0; }

    // own-chunk bbox (exact f32 min/max over x,y,z; .w is bitcast origidx)
    float lox = 3e38f, hix = -3e38f, loy = 3e38f, hiy = -3e38f, loz = 3e38f, hiz = -3e38f;
#pragma unroll
    for (int j = 0; j < PPT; ++j) {
        const float4 c = rxyz[t * PPT + j];
        lox = fminf(lox, c.x); hix = fmaxf(hix, c.x);
        loy = fminf(loy, c.y); hiy = fmaxf(hiy, c.y);
        loz = fminf(loz, c.z); hiz = fmaxf(hiz, c.z);
    }
    float lx = xyz[0], ly = xyz[1], lz = xyz[2];
    // register mirror of own chunk key; bv=1e10 forces the iter-1 rescan
    unsigned long long myk =
        ((unsigned long long)__float_as_uint(1e10f) << 32) | 0xffffffffu;
    unsigned long long wavepk = 0ULL;
    __syncthreads();

    for (int it = 1; it < NKP; ++it) {
        // chunk prune: lower bound of d2 to any owned point (same op order)
        const float bv = __uint_as_float((unsigned int)(myk >> 32));
        float dxm = fmaxf(fmaxf(lox - lx, lx - hix), 0.0f);
        float dym = fmaxf(fmaxf(loy - ly, ly - hiy), 0.0f);
        float dzm = fmaxf(fmaxf(loz - lz, lz - hiz), 0.0f);
        float dmin2 = dxm * dxm + dym * dym;
        dmin2 = dmin2 + dzm * dzm;
        const bool need = dmin2 < bv;
        unsigned long long ball = __ballot(need);
        if (ball != 0ULL) {
            const int half = lane >> 5;
            const int jj = lane & 31;
            unsigned long long rem = ball;
            while (rem) {
                int c0 = __ffsll((long long)rem) - 1;
                rem &= rem - 1;
                int c1 = -1;
                if (rem) { c1 = __ffsll((long long)rem) - 1; rem &= rem - 1; }
                const int ch = half ? c1 : c0;
                unsigned long long k2 = 0ULL;
                if (ch >= 0) {
                    const int gc = (w << 6) + ch;  // global chunk id
                    const int a = (gc << 5) + jj;  // sorted point index
                    const float4 cc = rxyz[a];
                    float dx = cc.x - lx;
                    float dy = cc.y - ly;
                    float dz = cc.z - lz;
                    float d2 = dx * dx + dy * dy;
                    d2 = d2 + dz * dz;
                    float m = fminf(mdl[a], d2);
                    mdl[a] = m;
                    k2 = ((unsigned long long)__float_as_uint(m) << 32) |
                         (unsigned int)(~__float_as_uint(cc.w));
                }
                // in-half 32-lane reduce (positive f64 fmax == u64 lex max);
                // xor offsets 1..16 stay within each 32-lane half
                double ha = __longlong_as_double((long long)k2);
                ha = fmax(ha, __shfl_xor(ha, 1));
                ha = fmax(ha, __shfl_xor(ha, 2));
                ha = fmax(ha, __shfl_xor(ha, 4));
                ha = fmax(ha, __shfl_xor(ha, 8));
                ha = fmax(ha, __shfl_xor(ha, 16));
                if (ch >= 0 && jj == 0)
                    ckey[(w << 6) + ch] = (unsigned long long)__double_as_longlong(ha);
            }
            if (need) myk = ckey[t];  // refresh own mirror (same-wave DS order)
            // wave reduce (positive f64 fmax == u64 lex max)
            double a = __longlong_as_double((long long)myk);
#pragma unroll
            for (int off = 32; off >= 1; off >>= 1)
                a = fmax(a, __shfl_xor(a, off));
            wavepk = (unsigned long long)__double_as_longlong(a);
        }
        if (lane == 0) atomicMax(&gbest[it & 1], wavepk);
        if (t == 0) gbest[(it + 1) & 1] = 0ULL;  // reset next parity slot
        __syncthreads();
        const unsigned long long g = gbest[it & 1];  // broadcast read
        const int gi = ~((int)(unsigned int)(g & 0xffffffffULL));
        if (t == 0) kp[it] = gi;
        const int gs = __builtin_amdgcn_readfirstlane(gi);
        lx = xyz[3 * gs + 0];
        ly = xyz[3 * gs + 1];
        lz = xyz[3 * gs + 2];
    }
}

// ===================== grid build (counting sort) ==================
__global__ void k_hist(const float* __restrict__ xyz, int* __restrict__ cellcnt,
                       int* __restrict__ pcell, int* __restrict__ prank) {
    int p = blockIdx.x * blockDim.x + threadIdx.x;
    if (p >= NPT) return;
    float x = xyz[3 * p], y = xyz[3 * p + 1], z = xyz[3 * p + 2];
    int cx = min(max((int)x, 0), GX - 1);
    int cy = min(max((int)y, 0), GY - 1);
    int cz = min(max((int)z, 0), GZ - 1);
    int c = (cz * GY + cy) * GX + cx;
    pcell[p] = c;
    prank[p] = atomicAdd(&cellcnt[c], 1);
}

__global__ __launch_bounds__(1024) void k_scan(const int* __restrict__ cnt,
                                               int* __restrict__ start) {
    __shared__ int ch[1024];
    int t = threadIdx.x;
    int c0 = cnt[4 * t], c1 = cnt[4 * t + 1], c2 = cnt[4 * t + 2], c3 = cnt[4 * t + 3];
    int s1 = c0 + c1, s2 = s1 + c2, s3 = s2 + c3;
    ch[t] = s3;
    __syncthreads();
    int acc = s3;
    for (int off = 1; off < 1024; off <<= 1) {
        int v = (t >= off) ? ch[t - off] : 0;
        __syncthreads();
        acc += v;
        ch[t] = acc;
        __syncthreads();
    }
    int excl = acc - s3;
    start[4 * t] = excl;
    start[4 * t + 1] = excl + c0;
    start[4 * t + 2] = excl + s1;
    start[4 * t + 3] = excl + s2;
}

__global__ void k_scatter(const float* __restrict__ xyz, const int* __restrict__ pcell,
                          const int* __restrict__ prank, const int* __restrict__ start,
                          float4* __restrict__ rxyz) {
    int p = blockIdx.x * blockDim.x + threadIdx.x;
    if (p >= NPT) return;
    int dst = start[pcell[p]] + prank[p];
    rxyz[dst] = make_float4(xyz[3 * p], xyz[3 * p + 1], xyz[3 * p + 2],
                            __int_as_float(p));  // .w carries origidx (bitcast)
}

// ========================= ball query ==============================
__global__ __launch_bounds__(256) void k_ball(
    const float* __restrict__ xyz, const float4* __restrict__ rxyz,
    const int* __restrict__ kp, const int* __restrict__ cellcnt,
    const int* __restrict__ start, int* __restrict__ ids, int* __restrict__ nas,
    int* __restrict__ nbs, float* __restrict__ kx, float* __restrict__ ky,
    float* __restrict__ kz) {
#pragma clang fp contract(off)
    int k = blockIdx.x * 256 + threadIdx.x;
    if (k >= NKP) return;
    int kpi = kp[k];
    float qx = xyz[3 * kpi], qy = xyz[3 * kpi + 1], qz = xyz[3 * kpi + 2];
    kx[k] = qx; ky[k] = qy; kz[k] = qz;
    const float r2a = (float)(0.4 * 0.4);  // 1-ulp-exact vs python double->f32
    const float r2b = (float)(0.8 * 0.8);
    float d[16]; int id[16];
#pragma unroll
    for (int i = 0; i < 16; ++i) { d[i] = 3.0e38f; id[i] = 0x7fffffff; }
    int na = 0, nb = 0;
    int cx = min(max((int)qx, 0), GX - 1);
    int cy = min(max((int)qy, 0), GY - 1);
    int cz = min(max((int)qz, 0), GZ - 1);
    for (int zz = max(cz - 1, 0); zz <= min(cz + 1, GZ - 1); ++zz)
        for (int yy = max(cy - 1, 0); yy <= min(cy + 1, GY - 1); ++yy)
            for (int xx = max(cx - 1, 0); xx <= min(cx + 1, GX - 1); ++xx) {
                int c = (zz * GY + yy) * GX + xx;
                int s = start[c], e = s + cellcnt[c];
                for (int i = s; i < e; ++i) {
                    const float4 cc = rxyz[i];
                    float dx = cc.x - qx;
                    float dy = cc.y - qy;
                    float dzv = cc.z - qz;
                    float dd = dx * dx + dy * dy;
                    dd = dd + dzv * dzv;
                    if (dd <= r2b) {
                        int p = __float_as_int(cc.w);
                        nb++;
                        if (dd <= r2a) na++;
                        bool lt15 = (dd < d[15]) || (dd == d[15] && p < id[15]);
                        if (lt15) {
                            bool lt[16];
#pragma unroll
                            for (int j = 0; j < 16; ++j)
                                lt[j] = (dd < d[j]) || (dd == d[j] && p < id[j]);
#pragma unroll
                            for (int j = 15; j >= 1; --j) {
                                d[j] = lt[j - 1] ? d[j - 1] : (lt[j] ? dd : d[j]);
                                id[j] = lt[j - 1] ? id[j - 1] : (lt[j] ? p : id[j]);
                            }
                            if (lt[0]) { d[0] = dd; id[0] = p; }
                        }
                    }
                }
            }
    int na16 = min(na, 16), nb16 = min(nb, 16);
    nas[k] = na16;
    nbs[k] = nb16;
    int fill = (nb16 > 0) ? id[0] : 0;
#pragma unroll
    for (int s2 = 0; s2 < 16; ++s2) ids[k * 16 + s2] = (s2 < nb16) ? id[s2] : fill;
}

// ===================== grouped MLP + max pool ======================
__device__ __forceinline__ void sa_scale_eval(
    int n, const int* idk, int s, float qx, float qy, float qz,
    const float* __restrict__ xyz, const float* __restrict__ feats,
    const float* sW1, const float* sg1, const float* sb1, const float* sW2,
    const float* sg2, const float* sb2, float* h2out) {
    int pid = idk[(s < n) ? s : 0];
    float g0 = xyz[3 * pid + 0] - qx;
    float g1v = xyz[3 * pid + 1] - qy;
    float g2v = xyz[3 * pid + 2] - qz;
    float g3 = feats[2 * pid + 0];
    float g4 = feats[2 * pid + 1];
    float h1[16];
#pragma unroll
    for (int dd = 0; dd < 16; ++dd) {
        float acc = g0 * sW1[0 * 16 + dd];
        acc = acc + g1v * sW1[1 * 16 + dd];
        acc = acc + g2v * sW1[2 * 16 + dd];
        acc = acc + g3 * sW1[3 * 16 + dd];
        acc = acc + g4 * sW1[4 * 16 + dd];
        h1[dd] = fmaxf(acc * sg1[dd] + sb1[dd], 0.0f);
    }
#pragma unroll
    for (int dd = 0; dd < 16; ++dd) {
        float acc = h1[0] * sW2[0 * 16 + dd];
#pragma unroll
        for (int c = 1; c < 16; ++c) acc = acc + h1[c] * sW2[c * 16 + dd];
        float v = fmaxf(acc * sg2[dd] + sb2[dd], 0.0f);
#pragma unroll
        for (int off = 1; off < 16; off <<= 1) v = fmaxf(v, __shfl_xor(v, off));
        h2out[dd] = v;  // pooled over the 16-lane sample group
    }
}

__global__ __launch_bounds__(256) void k_mlp(
    const float* __restrict__ xyz, const float* __restrict__ feats,
    const int* __restrict__ ids, const int* __restrict__ nas, const int* __restrict__ nbs,
    const float* __restrict__ kx, const float* __restrict__ ky, const float* __restrict__ kz,
    const float* W1a, const float* g1a, const float* b1a, const float* W2a,
    const float* g2a, const float* b2a, const float* W1b, const float* g1b,
    const float* b1b, const float* W2b, const float* g2b, const float* b2b,
    float* __restrict__ pooled) {
#pragma clang fp contract(off)
    __shared__ float sW1a[80], sW2a[256], sg1a[16], sb1a[16], sg2a[16], sb2a[16];
    __shared__ float sW1b[80], sW2b[256], sg1b[16], sb1b[16], sg2b[16], sb2b[16];
    int t = threadIdx.x;
    if (t < 80) { sW1a[t] = W1a[t]; sW1b[t] = W1b[t]; }
    sW2a[t] = W2a[t];
    sW2b[t] = W2b[t];
    if (t < 16) {
        sg1a[t] = g1a[t]; sb1a[t] = b1a[t]; sg2a[t] = g2a[t]; sb2a[t] = b2a[t];
        sg1b[t] = g1b[t]; sb1b[t] = b1b[t]; sg2b[t] = g2b[t]; sb2b[t] = b2b[t];
    }
    __syncthreads();
    int wave = t >> 6, lane = t & 63;
    int kpl = lane >> 4, s = lane & 15;
    int k = blockIdx.x * 16 + wave * 4 + kpl;
    float qx = kx[k], qy = ky[k], qz = kz[k];
    int na = nas[k], nb = nbs[k];
    const int* idk = ids + k * 16;
    float h2a[16], h2b[16];
    sa_scale_eval(na, idk, s, qx, qy, qz, xyz, feats, sW1a, sg1a, sb1a, sW2a, sg2a, sb2a, h2a);
    sa_scale_eval(nb, idk, s, qx, qy, qz, xyz, feats, sW1b, sg1b, sb1b, sW2b, sg2b, sb2b, h2b);
    if (s == 0) {
#pragma unroll
        for (int dd = 0; dd < 16; ++dd) pooled[k * 32 + dd] = (na > 0) ? h2a[dd] : 0.0f;
#pragma unroll
        for (int dd = 0; dd < 16; ++dd) pooled[k * 32 + 16 + dd] = (nb > 0) ? h2b[dd] : 0.0f;
    }
}

// ================== FP: 3-NN interp + final MLP ====================
__global__ __launch_bounds__(256) void k_fp(
    const float* __restrict__ xyz, const float* __restrict__ kx,
    const float* __restrict__ ky, const float* __restrict__ kz,
    const float* __restrict__ pooled, const float* __restrict__ Wf,
    const float* __restrict__ gf, const float* __restrict__ bf,
    float* __restrict__ out) {
#pragma clang fp contract(off)
    __shared__ float skx[NKP], sky[NKP], skz[NKP];
    __shared__ float sWf[512], sgf[16], sbf[16];
    int t = threadIdx.x;
    for (int i = t; i < NKP; i += 256) { skx[i] = kx[i]; sky[i] = ky[i]; skz[i] = kz[i]; }
    for (int i = t; i < 512; i += 256) sWf[i] = Wf[i];
    if (t < 16) { sgf[t] = gf[t]; sbf[t] = bf[t]; }
    __syncthreads();
    int p = blockIdx.x * 256 + t;
    float x = xyz[3 * p], y = xyz[3 * p + 1], z = xyz[3 * p + 2];
    float dA = 3e38f, dB = 3e38f, dC = 3e38f;
    int iA = 0, iB = 0, iC = 0;
    for (int k = 0; k < NKP; ++k) {
        float dx = skx[k] - x;
        float dy = sky[k] - y;
        float dz = skz[k] - z;
        float dd = dx * dx + dy * dy;
        dd = dd + dz * dz;
        if (dd < dC) {            // strict < + ascending k == stable top_k ties
            if (dd < dB) {
                dC = dB; iC = iB;
                if (dd < dA) { dB = dA; iB = iA; dA = dd; iA = k; }
                else { dB = dd; iB = k; }
            } else { dC = dd; iC = k; }
        }
    }
    float s0 = __fsqrt_rn(fmaxf(dA, 1e-12f));
    float s1 = __fsqrt_rn(fmaxf(dB, 1e-12f));
    float s2 = __fsqrt_rn(fmaxf(dC, 1e-12f));
    float w0 = 1.0f / (s0 + 1e-8f);
    float w1 = 1.0f / (s1 + 1e-8f);
    float w2 = 1.0f / (s2 + 1e-8f);
    float wsum = (w0 + w1) + w2;
    w0 /= wsum; w1 /= wsum; w2 /= wsum;
    const float* P0 = pooled + iA * 32;
    const float* P1 = pooled + iB * 32;
    const float* P2 = pooled + iC * 32;
    float interp[32];
#pragma unroll
    for (int c = 0; c < 32; ++c) interp[c] = w0 * P0[c] + w1 * P1[c] + w2 * P2[c];
#pragma unroll
    for (int dd = 0; dd < 16; ++dd) {
        float acc = interp[0] * sWf[0 * 16 + dd];
#pragma unroll
        for (int c = 1; c < 32; ++c) acc = acc + interp[c] * sWf[c * 16 + dd];
        out[p * 16 + dd] = fmaxf(acc * sgf[dd] + sbf[dd], 0.0f);
    }
}

// ============================ launch ===============================
extern "C" void kernel_launch(void* const* d_in, const int* in_sizes, int n_in,
                              void* d_out, int out_size, void* d_ws, size_t ws_size,
                              hipStream_t stream) {
    const float* xyz = (const float*)d_in[0];
    const float* feats = (const float*)d_in[1];
    const float* Wf = (const float*)d_in[2];
    const float* gf = (const float*)d_in[3];
    const float* bf = (const float*)d_in[4];
    const float* W1a = (const float*)d_in[5];
    const float* g1a = (const float*)d_in[6];
    const float* b1a = (const float*)d_in[7];
    const float* W2a = (const float*)d_in[8];
    const float* g2a = (const float*)d_in[9];
    const float* b2a = (const float*)d_in[10];
    const float* W1b = (const float*)d_in[11];
    const float* g1b = (const float*)d_in[12];
    const float* b1b = (const float*)d_in[13];
    const float* W2b = (const float*)d_in[14];
    const float* g2b = (const float*)d_in[15];
    const float* b2b = (const float*)d_in[16];

    char* ws = (char*)d_ws;
    if (ws_size < 1835008) return;  // proven budget (rounds 3-9 passed)
    int* kp = (int*)(ws + 0);                // 16K
    int* cellcnt = (int*)(ws + 16384);       // 16K
    int* cellstart = (int*)(ws + 32768);     // 16K
    int* pcell = (int*)(ws + 49152);         // 128K
    int* prank = (int*)(ws + 180224);        // 128K
    float4* rxyz = (float4*)(ws + 442368);   // 512K (sorted order; .w = origidx)
    int* ids = (int*)(ws + 966656);          // 256K
    int* nas = (int*)(ws + 1228800);         // 16K
    int* nbs = (int*)(ws + 1245184);         // 16K
    float* kx = (float*)(ws + 1261568);      // 16K
    float* ky = (float*)(ws + 1277952);      // 16K
    float* kz = (float*)(ws + 1294336);      // 16K
    float* pooled = (float*)(ws + 1310720);  // 512K

    hipMemsetAsync(cellcnt, 0, NCELL_PAD * sizeof(int), stream);
    k_hist<<<NPT / 256, 256, 0, stream>>>(xyz, cellcnt, pcell, prank);
    k_scan<<<1, 1024, 0, stream>>>(cellcnt, cellstart);
    k_scatter<<<NPT / 256, 256, 0, stream>>>(xyz, pcell, prank, cellstart, rxyz);
    k_fps<<<1, FPS_T, 0, stream>>>(xyz, rxyz, kp);
    k_ball<<<NKP / 256, 256, 0, stream>>>(xyz, rxyz, kp, cellcnt, cellstart, ids, nas,
                                          nbs, kx, ky, kz);
    k_mlp<<<NKP / 16, 256, 0, stream>>>(xyz, feats, ids, nas, nbs, kx, ky, kz, W1a, g1a,
                                        b1a, W2a, g2a, b2a, W1b, g1b, b1b, W2b, g2b, b2b,
                                        pooled);
    k_fp<<<NPT / 256, 256, 0, stream>>>(xyz, kx, ky, kz, pooled, Wf, gf, bf, (float*)d_out);
}

// Round 11
// 8218.452 us; speedup vs baseline: 1.2851x; 1.2851x over previous
//
#include <hip/hip_runtime.h>

#pragma clang fp contract(off)

#define NPT 32768
#define NKP 4096
#define GX 40
#define GY 20
#define GZ 4
#define NCELL_PAD 4096

// ============================ FPS =================================
// Chunk-batched bbox-pruned FPS (round 9: 7.4ms validated bit-exact).
// Round-10 lesson: in-pass shuffle reduce REGRESSED (+2.3ms) -- shfl =
// ds_bpermute (LDS pipe), 5-deep dependent chain per pass beats nothing;
// the 32-way atomicMax is fire-and-forget and overlaps. Keep atomics.
// Round-11 change (async ckey maintenance): refresh myk from ckey at the
// TOP of the next iteration (atomics drain under reduce+barrier+broadcast)
// instead of right after the pass loop (which waited on the atomic queue).
// Wave-reduce input is register-resident: per-lane passmax accumulates the
// keys this lane computed; contribution = need ? passmax : max(passmax,myk)
// (stale needy-owner keys excluded; needy chunks covered by their 32
// processing lanes; non-needy by cached owner keys). Bit-identical result.
#define FPS_T 1024
#define PPT 32

__global__ __attribute__((amdgpu_flat_work_group_size(FPS_T, FPS_T)))
__attribute__((amdgpu_waves_per_eu(4, 4))) void k_fps(
    const float* __restrict__ xyz, const float4* __restrict__ rxyz,
    int* __restrict__ kp) {
#pragma clang fp contract(off)
    __shared__ float mdl[NPT];                 // 128 KiB min-dist, sorted order
    __shared__ unsigned long long ckey[1024];  // per-chunk packed (maxmd, ~oid)
    __shared__ unsigned long long gbest[2];    // parity global-argmax slots
    const int t = threadIdx.x;
    const int lane = t & 63;
    const int w = t >> 6;

    for (int i = t; i < NPT; i += FPS_T) mdl[i] = 1e10f;
    // init forces the iter-1 full rescan (bv=1e10 read at iter-1 top)
    ckey[t] = ((unsigned long long)__float_as_uint(1e10f) << 32) | 0xffffffffu;
    if (t == 0) { gbest[0] = 0ULL; gbest[1] = 0ULL; kp[0] = 0; }

    // own-chunk bbox (exact f32 min/max over x,y,z; .w is bitcast origidx)
    float lox = 3e38f, hix = -3e38f, loy = 3e38f, hiy = -3e38f, loz = 3e38f, hiz = -3e38f;
#pragma unroll
    for (int j = 0; j < PPT; ++j) {
        const float4 c = rxyz[t * PPT + j];
        lox = fminf(lox, c.x); hix = fmaxf(hix, c.x);
        loy = fminf(loy, c.y); hiy = fmaxf(hiy, c.y);
        loz = fminf(loz, c.z); hiz = fmaxf(hiz, c.z);
    }
    float lx = xyz[0], ly = xyz[1], lz = xyz[2];
    unsigned long long wavepk = 0ULL;
    __syncthreads();

    for (int it = 1; it < NKP; ++it) {
        // async-refreshed chunk key: prev-iter atomics drained under the
        // barrier/broadcast, so this LDS read is cheap and current.
        const unsigned long long myk = ckey[t];
        const float bv = __uint_as_float((unsigned int)(myk >> 32));
        float dxm = fmaxf(fmaxf(lox - lx, lx - hix), 0.0f);
        float dym = fmaxf(fmaxf(loy - ly, ly - hiy), 0.0f);
        float dzm = fmaxf(fmaxf(loz - lz, lz - hiz), 0.0f);
        float dmin2 = dxm * dxm + dym * dym;
        dmin2 = dmin2 + dzm * dzm;
        const bool need = dmin2 < bv;
        unsigned long long ball = __ballot(need);
        if (ball != 0ULL) {
            if (need) ckey[t] = 0ULL;  // reset own slot (same-wave DS order)
            const int half = lane >> 5;
            const int jj = lane & 31;
            double passmax = 0.0;  // per-lane running max key (registers)
            unsigned long long rem = ball;
            while (rem) {
                int c0 = __ffsll((long long)rem) - 1;
                rem &= rem - 1;
                int c1 = -1;
                if (rem) { c1 = __ffsll((long long)rem) - 1; rem &= rem - 1; }
                const int ch = half ? c1 : c0;
                if (ch >= 0) {
                    const int gc = (w << 6) + ch;  // global chunk id
                    const int a = (gc << 5) + jj;  // sorted point index
                    const float4 cc = rxyz[a];
                    float dx = cc.x - lx;
                    float dy = cc.y - ly;
                    float dz = cc.z - lz;
                    float d2 = dx * dx + dy * dy;
                    d2 = d2 + dz * dz;
                    float m = fminf(mdl[a], d2);
                    mdl[a] = m;
                    const unsigned long long k2 =
                        ((unsigned long long)__float_as_uint(m) << 32) |
                        (unsigned int)(~__float_as_uint(cc.w));
                    atomicMax(&ckey[gc], k2);  // fire-and-forget maintenance
                    passmax = fmax(passmax, __longlong_as_double((long long)k2));
                }
            }
            // lane contribution: fresh pass keys; cached key only if own
            // chunk unchanged (stale needy-owner key must be excluded)
            double a = need ? passmax
                            : fmax(passmax, __longlong_as_double((long long)myk));
#pragma unroll
            for (int off = 32; off >= 1; off >>= 1)
                a = fmax(a, __shfl_xor(a, off));
            wavepk = (unsigned long long)__double_as_longlong(a);
        }
        if (lane == 0) atomicMax(&gbest[it & 1], wavepk);
        if (t == 0) gbest[(it + 1) & 1] = 0ULL;  // reset next parity slot
        __syncthreads();
        const unsigned long long g = gbest[it & 1];  // broadcast read
        const int gi = ~((int)(unsigned int)(g & 0xffffffffULL));
        if (t == 0) kp[it] = gi;
        const int gs = __builtin_amdgcn_readfirstlane(gi);
        lx = xyz[3 * gs + 0];
        ly = xyz[3 * gs + 1];
        lz = xyz[3 * gs + 2];
    }
}

// ===================== grid build (counting sort) ==================
__global__ void k_hist(const float* __restrict__ xyz, int* __restrict__ cellcnt,
                       int* __restrict__ pcell, int* __restrict__ prank) {
    int p = blockIdx.x * blockDim.x + threadIdx.x;
    if (p >= NPT) return;
    float x = xyz[3 * p], y = xyz[3 * p + 1], z = xyz[3 * p + 2];
    int cx = min(max((int)x, 0), GX - 1);
    int cy = min(max((int)y, 0), GY - 1);
    int cz = min(max((int)z, 0), GZ - 1);
    int c = (cz * GY + cy) * GX + cx;
    pcell[p] = c;
    prank[p] = atomicAdd(&cellcnt[c], 1);
}

__global__ __launch_bounds__(1024) void k_scan(const int* __restrict__ cnt,
                                               int* __restrict__ start) {
    __shared__ int ch[1024];
    int t = threadIdx.x;
    int c0 = cnt[4 * t], c1 = cnt[4 * t + 1], c2 = cnt[4 * t + 2], c3 = cnt[4 * t + 3];
    int s1 = c0 + c1, s2 = s1 + c2, s3 = s2 + c3;
    ch[t] = s3;
    __syncthreads();
    int acc = s3;
    for (int off = 1; off < 1024; off <<= 1) {
        int v = (t >= off) ? ch[t - off] : 0;
        __syncthreads();
        acc += v;
        ch[t] = acc;
        __syncthreads();
    }
    int excl = acc - s3;
    start[4 * t] = excl;
    start[4 * t + 1] = excl + c0;
    start[4 * t + 2] = excl + s1;
    start[4 * t + 3] = excl + s2;
}

__global__ void k_scatter(const float* __restrict__ xyz, const int* __restrict__ pcell,
                          const int* __restrict__ prank, const int* __restrict__ start,
                          float4* __restrict__ rxyz) {
    int p = blockIdx.x * blockDim.x + threadIdx.x;
    if (p >= NPT) return;
    int dst = start[pcell[p]] + prank[p];
    rxyz[dst] = make_float4(xyz[3 * p], xyz[3 * p + 1], xyz[3 * p + 2],
                            __int_as_float(p));  // .w carries origidx (bitcast)
}

// ========================= ball query ==============================
__global__ __launch_bounds__(256) void k_ball(
    const float* __restrict__ xyz, const float4* __restrict__ rxyz,
    const int* __restrict__ kp, const int* __restrict__ cellcnt,
    const int* __restrict__ start, int* __restrict__ ids, int* __restrict__ nas,
    int* __restrict__ nbs, float* __restrict__ kx, float* __restrict__ ky,
    float* __restrict__ kz) {
#pragma clang fp contract(off)
    int k = blockIdx.x * 256 + threadIdx.x;
    if (k >= NKP) return;
    int kpi = kp[k];
    float qx = xyz[3 * kpi], qy = xyz[3 * kpi + 1], qz = xyz[3 * kpi + 2];
    kx[k] = qx; ky[k] = qy; kz[k] = qz;
    const float r2a = (float)(0.4 * 0.4);  // 1-ulp-exact vs python double->f32
    const float r2b = (float)(0.8 * 0.8);
    float d[16]; int id[16];
#pragma unroll
    for (int i = 0; i < 16; ++i) { d[i] = 3.0e38f; id[i] = 0x7fffffff; }
    int na = 0, nb = 0;
    int cx = min(max((int)qx, 0), GX - 1);
    int cy = min(max((int)qy, 0), GY - 1);
    int cz = min(max((int)qz, 0), GZ - 1);
    for (int zz = max(cz - 1, 0); zz <= min(cz + 1, GZ - 1); ++zz)
        for (int yy = max(cy - 1, 0); yy <= min(cy + 1, GY - 1); ++yy)
            for (int xx = max(cx - 1, 0); xx <= min(cx + 1, GX - 1); ++xx) {
                int c = (zz * GY + yy) * GX + xx;
                int s = start[c], e = s + cellcnt[c];
                for (int i = s; i < e; ++i) {
                    const float4 cc = rxyz[i];
                    float dx = cc.x - qx;
                    float dy = cc.y - qy;
                    float dzv = cc.z - qz;
                    float dd = dx * dx + dy * dy;
                    dd = dd + dzv * dzv;
                    if (dd <= r2b) {
                        int p = __float_as_int(cc.w);
                        nb++;
                        if (dd <= r2a) na++;
                        bool lt15 = (dd < d[15]) || (dd == d[15] && p < id[15]);
                        if (lt15) {
                            bool lt[16];
#pragma unroll
                            for (int j = 0; j < 16; ++j)
                                lt[j] = (dd < d[j]) || (dd == d[j] && p < id[j]);
#pragma unroll
                            for (int j = 15; j >= 1; --j) {
                                d[j] = lt[j - 1] ? d[j - 1] : (lt[j] ? dd : d[j]);
                                id[j] = lt[j - 1] ? id[j - 1] : (lt[j] ? p : id[j]);
                            }
                            if (lt[0]) { d[0] = dd; id[0] = p; }
                        }
                    }
                }
            }
    int na16 = min(na, 16), nb16 = min(nb, 16);
    nas[k] = na16;
    nbs[k] = nb16;
    int fill = (nb16 > 0) ? id[0] : 0;
#pragma unroll
    for (int s2 = 0; s2 < 16; ++s2) ids[k * 16 + s2] = (s2 < nb16) ? id[s2] : fill;
}

// ===================== grouped MLP + max pool ======================
__device__ __forceinline__ void sa_scale_eval(
    int n, const int* idk, int s, float qx, float qy, float qz,
    const float* __restrict__ xyz, const float* __restrict__ feats,
    const float* sW1, const float* sg1, const float* sb1, const float* sW2,
    const float* sg2, const float* sb2, float* h2out) {
    int pid = idk[(s < n) ? s : 0];
    float g0 = xyz[3 * pid + 0] - qx;
    float g1v = xyz[3 * pid + 1] - qy;
    float g2v = xyz[3 * pid + 2] - qz;
    float g3 = feats[2 * pid + 0];
    float g4 = feats[2 * pid + 1];
    float h1[16];
#pragma unroll
    for (int dd = 0; dd < 16; ++dd) {
        float acc = g0 * sW1[0 * 16 + dd];
        acc = acc + g1v * sW1[1 * 16 + dd];
        acc = acc + g2v * sW1[2 * 16 + dd];
        acc = acc + g3 * sW1[3 * 16 + dd];
        acc = acc + g4 * sW1[4 * 16 + dd];
        h1[dd] = fmaxf(acc * sg1[dd] + sb1[dd], 0.0f);
    }
#pragma unroll
    for (int dd = 0; dd < 16; ++dd) {
        float acc = h1[0] * sW2[0 * 16 + dd];
#pragma unroll
        for (int c = 1; c < 16; ++c) acc = acc + h1[c] * sW2[c * 16 + dd];
        float v = fmaxf(acc * sg2[dd] + sb2[dd], 0.0f);
#pragma unroll
        for (int off = 1; off < 16; off <<= 1) v = fmaxf(v, __shfl_xor(v, off));
        h2out[dd] = v;  // pooled over the 16-lane sample group
    }
}

__global__ __launch_bounds__(256) void k_mlp(
    const float* __restrict__ xyz, const float* __restrict__ feats,
    const int* __restrict__ ids, const int* __restrict__ nas, const int* __restrict__ nbs,
    const float* __restrict__ kx, const float* __restrict__ ky, const float* __restrict__ kz,
    const float* W1a, const float* g1a, const float* b1a, const float* W2a,
    const float* g2a, const float* b2a, const float* W1b, const float* g1b,
    const float* b1b, const float* W2b, const float* g2b, const float* b2b,
    float* __restrict__ pooled) {
#pragma clang fp contract(off)
    __shared__ float sW1a[80], sW2a[256], sg1a[16], sb1a[16], sg2a[16], sb2a[16];
    __shared__ float sW1b[80], sW2b[256], sg1b[16], sb1b[16], sg2b[16], sb2b[16];
    int t = threadIdx.x;
    if (t < 80) { sW1a[t] = W1a[t]; sW1b[t] = W1b[t]; }
    sW2a[t] = W2a[t];
    sW2b[t] = W2b[t];
    if (t < 16) {
        sg1a[t] = g1a[t]; sb1a[t] = b1a[t]; sg2a[t] = g2a[t]; sb2a[t] = b2a[t];
        sg1b[t] = g1b[t]; sb1b[t] = b1b[t]; sg2b[t] = g2b[t]; sb2b[t] = b2b[t];
    }
    __syncthreads();
    int wave = t >> 6, lane = t & 63;
    int kpl = lane >> 4, s = lane & 15;
    int k = blockIdx.x * 16 + wave * 4 + kpl;
    float qx = kx[k], qy = ky[k], qz = kz[k];
    int na = nas[k], nb = nbs[k];
    const int* idk = ids + k * 16;
    float h2a[16], h2b[16];
    sa_scale_eval(na, idk, s, qx, qy, qz, xyz, feats, sW1a, sg1a, sb1a, sW2a, sg2a, sb2a, h2a);
    sa_scale_eval(nb, idk, s, qx, qy, qz, xyz, feats, sW1b, sg1b, sb1b, sW2b, sg2b, sb2b, h2b);
    if (s == 0) {
#pragma unroll
        for (int dd = 0; dd < 16; ++dd) pooled[k * 32 + dd] = (na > 0) ? h2a[dd] : 0.0f;
#pragma unroll
        for (int dd = 0; dd < 16; ++dd) pooled[k * 32 + 16 + dd] = (nb > 0) ? h2b[dd] : 0.0f;
    }
}

// ================== FP: 3-NN interp + final MLP ====================
__global__ __launch_bounds__(256) void k_fp(
    const float* __restrict__ xyz, const float* __restrict__ kx,
    const float* __restrict__ ky, const float* __restrict__ kz,
    const float* __restrict__ pooled, const float* __restrict__ Wf,
    const float* __restrict__ gf, const float* __restrict__ bf,
    float* __restrict__ out) {
#pragma clang fp contract(off)
    __shared__ float skx[NKP], sky[NKP], skz[NKP];
    __shared__ float sWf[512], sgf[16], sbf[16];
    int t = threadIdx.x;
    for (int i = t; i < NKP; i += 256) { skx[i] = kx[i]; sky[i] = ky[i]; skz[i] = kz[i]; }
    for (int i = t; i < 512; i += 256) sWf[i] = Wf[i];
    if (t < 16) { sgf[t] = gf[t]; sbf[t] = bf[t]; }
    __syncthreads();
    int p = blockIdx.x * 256 + t;
    float x = xyz[3 * p], y = xyz[3 * p + 1], z = xyz[3 * p + 2];
    float dA = 3e38f, dB = 3e38f, dC = 3e38f;
    int iA = 0, iB = 0, iC = 0;
    for (int k = 0; k < NKP; ++k) {
        float dx = skx[k] - x;
        float dy = sky[k] - y;
        float dz = skz[k] - z;
        float dd = dx * dx + dy * dy;
        dd = dd + dz * dz;
        if (dd < dC) {            // strict < + ascending k == stable top_k ties
            if (dd < dB) {
                dC = dB; iC = iB;
                if (dd < dA) { dB = dA; iB = iA; dA = dd; iA = k; }
                else { dB = dd; iB = k; }
            } else { dC = dd; iC = k; }
        }
    }
    float s0 = __fsqrt_rn(fmaxf(dA, 1e-12f));
    float s1 = __fsqrt_rn(fmaxf(dB, 1e-12f));
    float s2 = __fsqrt_rn(fmaxf(dC, 1e-12f));
    float w0 = 1.0f / (s0 + 1e-8f);
    float w1 = 1.0f / (s1 + 1e-8f);
    float w2 = 1.0f / (s2 + 1e-8f);
    float wsum = (w0 + w1) + w2;
    w0 /= wsum; w1 /= wsum; w2 /= wsum;
    const float* P0 = pooled + iA * 32;
    const float* P1 = pooled + iB * 32;
    const float* P2 = pooled + iC * 32;
    float interp[32];
#pragma unroll
    for (int c = 0; c < 32; ++c) interp[c] = w0 * P0[c] + w1 * P1[c] + w2 * P2[c];
#pragma unroll
    for (int dd = 0; dd < 16; ++dd) {
        float acc = interp[0] * sWf[0 * 16 + dd];
#pragma unroll
        for (int c = 1; c < 32; ++c) acc = acc + interp[c] * sWf[c * 16 + dd];
        out[p * 16 + dd] = fmaxf(acc * sgf[dd] + sbf[dd], 0.0f);
    }
}

// ============================ launch ===============================
extern "C" void kernel_launch(void* const* d_in, const int* in_sizes, int n_in,
                              void* d_out, int out_size, void* d_ws, size_t ws_size,
                              hipStream_t stream) {
    const float* xyz = (const float*)d_in[0];
    const float* feats = (const float*)d_in[1];
    const float* Wf = (const float*)d_in[2];
    const float* gf = (const float*)d_in[3];
    const float* bf = (const float*)d_in[4];
    const float* W1a = (const float*)d_in[5];
    const float* g1a = (const float*)d_in[6];
    const float* b1a = (const float*)d_in[7];
    const float* W2a = (const float*)d_in[8];
    const float* g2a = (const float*)d_in[9];
    const float* b2a = (const float*)d_in[10];
    const float* W1b = (const float*)d_in[11];
    const float* g1b = (const float*)d_in[12];
    const float* b1b = (const float*)d_in[13];
    const float* W2b = (const float*)d_in[14];
    const float* g2b = (const float*)d_in[15];
    const float* b2b = (const float*)d_in[16];

    char* ws = (char*)d_ws;
    if (ws_size < 1835008) return;  // proven budget (rounds 3-10 passed)
    int* kp = (int*)(ws + 0);                // 16K
    int* cellcnt = (int*)(ws + 16384);       // 16K
    int* cellstart = (int*)(ws + 32768);     // 16K
    int* pcell = (int*)(ws + 49152);         // 128K
    int* prank = (int*)(ws + 180224);        // 128K
    float4* rxyz = (float4*)(ws + 442368);   // 512K (sorted order; .w = origidx)
    int* ids = (int*)(ws + 966656);          // 256K
    int* nas = (int*)(ws + 1228800);         // 16K
    int* nbs = (int*)(ws + 1245184);         // 16K
    float* kx = (float*)(ws + 1261568);      // 16K
    float* ky = (float*)(ws + 1277952);      // 16K
    float* kz = (float*)(ws + 1294336);      // 16K
    float* pooled = (float*)(ws + 1310720);  // 512K

    hipMemsetAsync(cellcnt, 0, NCELL_PAD * sizeof(int), stream);
    k_hist<<<NPT / 256, 256, 0, stream>>>(xyz, cellcnt, pcell, prank);
    k_scan<<<1, 1024, 0, stream>>>(cellcnt, cellstart);
    k_scatter<<<NPT / 256, 256, 0, stream>>>(xyz, pcell, prank, cellstart, rxyz);
    k_fps<<<1, FPS_T, 0, stream>>>(xyz, rxyz, kp);
    k_ball<<<NKP / 256, 256, 0, stream>>>(xyz, rxyz, kp, cellcnt, cellstart, ids, nas,
                                          nbs, kx, ky, kz);
    k_mlp<<<NKP / 16, 256, 0, stream>>>(xyz, feats, ids, nas, nbs, kx, ky, kz, W1a, g1a,
                                        b1a, W2a, g2a, b2a, W1b, g1b, b1b, W2b, g2b, b2b,
                                        pooled);
    k_fp<<<NPT / 256, 256, 0, stream>>>(xyz, kx, ky, kz, pooled, Wf, gf, bf, (float*)d_out);
}

// Round 13
// 7375.478 us; speedup vs baseline: 1.4319x; 1.1143x over previous
//
#include <hip/hip_runtime.h>

#pragma clang fp contract(off)

#define NPT 32768
#define NKP 4096
#define GX 40
#define GY 20
#define GZ 4
#define NCELL_PAD 4096

// ============================ FPS =================================
// Chunk-batched bbox-pruned FPS (round 9/11: 7.4ms validated bit-exact).
// Round-12 change: wave argmax-reduce moved off the LDS pipe. The 6-level
// f64 __shfl_xor butterfly (12 dependent ds_bpermute) is replaced by the
// classic gfx9 DPP shift-reduce (row_shr:1/2/4/8 + row_bcast:15/31 --
// rocPRIM warp_reduce pattern): 6 levels x (2x update_dpp + u64 cmp/select),
// all VALU, result lands in lane 63 which issues the gbest atomicMax.
// u64 compare == previous positive-f64 fmax == lex (md desc, idx asc),
// and invalid DPP lanes read 0 = max identity -> bit-identical selections.
#define FPS_T 1024
#define PPT 32

// max(x, dpp_move(x)) per lane; CTRL must be a literal constant.
#define DPP_UMAX64(x, CTRL)                                                        \
    {                                                                              \
        unsigned int lo_ = (unsigned int)(x);                                      \
        unsigned int hi_ = (unsigned int)((x) >> 32);                              \
        unsigned int slo_ =                                                        \
            (unsigned int)__builtin_amdgcn_update_dpp(0, (int)lo_, CTRL, 0xf, 0xf, false); \
        unsigned int shi_ =                                                        \
            (unsigned int)__builtin_amdgcn_update_dpp(0, (int)hi_, CTRL, 0xf, 0xf, false); \
        unsigned long long s_ = ((unsigned long long)shi_ << 32) | slo_;           \
        if (s_ > (x)) (x) = s_;                                                    \
    }

__global__ __attribute__((amdgpu_flat_work_group_size(FPS_T, FPS_T)))
__attribute__((amdgpu_waves_per_eu(4, 4))) void k_fps(
    const float* __restrict__ xyz, const float4* __restrict__ rxyz,
    int* __restrict__ kp) {
#pragma clang fp contract(off)
    __shared__ float mdl[NPT];                 // 128 KiB min-dist, sorted order
    __shared__ unsigned long long ckey[1024];  // per-chunk packed (maxmd, ~oid)
    __shared__ unsigned long long gbest[2];    // parity global-argmax slots
    const int t = threadIdx.x;
    const int lane = t & 63;
    const int w = t >> 6;

    for (int i = t; i < NPT; i += FPS_T) mdl[i] = 1e10f;
    // init forces the iter-1 full rescan (bv=1e10 read at iter-1 top)
    ckey[t] = ((unsigned long long)__float_as_uint(1e10f) << 32) | 0xffffffffu;
    if (t == 0) { gbest[0] = 0ULL; gbest[1] = 0ULL; kp[0] = 0; }

    // own-chunk bbox (exact f32 min/max over x,y,z; .w is bitcast origidx)
    float lox = 3e38f, hix = -3e38f, loy = 3e38f, hiy = -3e38f, loz = 3e38f, hiz = -3e38f;
#pragma unroll
    for (int j = 0; j < PPT; ++j) {
        const float4 c = rxyz[t * PPT + j];
        lox = fminf(lox, c.x); hix = fmaxf(hix, c.x);
        loy = fminf(loy, c.y); hiy = fmaxf(hiy, c.y);
        loz = fminf(loz, c.z); hiz = fmaxf(hiz, c.z);
    }
    float lx = xyz[0], ly = xyz[1], lz = xyz[2];
    unsigned long long wavepk = 0ULL;  // meaningful only in lane 63
    __syncthreads();

    for (int it = 1; it < NKP; ++it) {
        // async-refreshed chunk key: prev-iter atomics drained under the
        // barrier/broadcast, so this LDS read is cheap and current.
        const unsigned long long myk = ckey[t];
        const float bv = __uint_as_float((unsigned int)(myk >> 32));
        float dxm = fmaxf(fmaxf(lox - lx, lx - hix), 0.0f);
        float dym = fmaxf(fmaxf(loy - ly, ly - hiy), 0.0f);
        float dzm = fmaxf(fmaxf(loz - lz, lz - hiz), 0.0f);
        float dmin2 = dxm * dxm + dym * dym;
        dmin2 = dmin2 + dzm * dzm;
        const bool need = dmin2 < bv;
        unsigned long long ball = __ballot(need);
        if (ball != 0ULL) {
            if (need) ckey[t] = 0ULL;  // reset own slot (same-wave DS order)
            const int half = lane >> 5;
            const int jj = lane & 31;
            unsigned long long passk = 0ULL;  // per-lane running max key (regs)
            unsigned long long rem = ball;
            while (rem) {
                int c0 = __ffsll((long long)rem) - 1;
                rem &= rem - 1;
                int c1 = -1;
                if (rem) { c1 = __ffsll((long long)rem) - 1; rem &= rem - 1; }
                const int ch = half ? c1 : c0;
                if (ch >= 0) {
                    const int gc = (w << 6) + ch;  // global chunk id
                    const int a = (gc << 5) + jj;  // sorted point index
                    const float4 cc = rxyz[a];
                    float dx = cc.x - lx;
                    float dy = cc.y - ly;
                    float dz = cc.z - lz;
                    float d2 = dx * dx + dy * dy;
                    d2 = d2 + dz * dz;
                    float m = fminf(mdl[a], d2);
                    mdl[a] = m;
                    const unsigned long long k2 =
                        ((unsigned long long)__float_as_uint(m) << 32) |
                        (unsigned int)(~__float_as_uint(cc.w));
                    atomicMax(&ckey[gc], k2);  // fire-and-forget maintenance
                    if (k2 > passk) passk = k2;
                }
            }
            // lane contribution: fresh pass keys; cached key only if own
            // chunk unchanged (stale needy-owner key must be excluded)
            unsigned long long a =
                need ? passk : (passk > myk ? passk : myk);
            // DPP shift-reduce: lane 63 ends with the wave max (VALU only)
            DPP_UMAX64(a, 0x111)  // row_shr:1
            DPP_UMAX64(a, 0x112)  // row_shr:2
            DPP_UMAX64(a, 0x114)  // row_shr:4
            DPP_UMAX64(a, 0x118)  // row_shr:8
            DPP_UMAX64(a, 0x142)  // row_bcast:15
            DPP_UMAX64(a, 0x143)  // row_bcast:31
            if (lane == 63) wavepk = a;
        }
        if (lane == 63) atomicMax(&gbest[it & 1], wavepk);
        if (t == 0) gbest[(it + 1) & 1] = 0ULL;  // reset next parity slot
        __syncthreads();
        const unsigned long long g = gbest[it & 1];  // broadcast read
        const int gi = ~((int)(unsigned int)(g & 0xffffffffULL));
        if (t == 0) kp[it] = gi;
        const int gs = __builtin_amdgcn_readfirstlane(gi);
        lx = xyz[3 * gs + 0];
        ly = xyz[3 * gs + 1];
        lz = xyz[3 * gs + 2];
    }
}

// ===================== grid build (counting sort) ==================
__global__ void k_hist(const float* __restrict__ xyz, int* __restrict__ cellcnt,
                       int* __restrict__ pcell, int* __restrict__ prank) {
    int p = blockIdx.x * blockDim.x + threadIdx.x;
    if (p >= NPT) return;
    float x = xyz[3 * p], y = xyz[3 * p + 1], z = xyz[3 * p + 2];
    int cx = min(max((int)x, 0), GX - 1);
    int cy = min(max((int)y, 0), GY - 1);
    int cz = min(max((int)z, 0), GZ - 1);
    int c = (cz * GY + cy) * GX + cx;
    pcell[p] = c;
    prank[p] = atomicAdd(&cellcnt[c], 1);
}

__global__ __launch_bounds__(1024) void k_scan(const int* __restrict__ cnt,
                                               int* __restrict__ start) {
    __shared__ int ch[1024];
    int t = threadIdx.x;
    int c0 = cnt[4 * t], c1 = cnt[4 * t + 1], c2 = cnt[4 * t + 2], c3 = cnt[4 * t + 3];
    int s1 = c0 + c1, s2 = s1 + c2, s3 = s2 + c3;
    ch[t] = s3;
    __syncthreads();
    int acc = s3;
    for (int off = 1; off < 1024; off <<= 1) {
        int v = (t >= off) ? ch[t - off] : 0;
        __syncthreads();
        acc += v;
        ch[t] = acc;
        __syncthreads();
    }
    int excl = acc - s3;
    start[4 * t] = excl;
    start[4 * t + 1] = excl + c0;
    start[4 * t + 2] = excl + s1;
    start[4 * t + 3] = excl + s2;
}

__global__ void k_scatter(const float* __restrict__ xyz, const int* __restrict__ pcell,
                          const int* __restrict__ prank, const int* __restrict__ start,
                          float4* __restrict__ rxyz) {
    int p = blockIdx.x * blockDim.x + threadIdx.x;
    if (p >= NPT) return;
    int dst = start[pcell[p]] + prank[p];
    rxyz[dst] = make_float4(xyz[3 * p], xyz[3 * p + 1], xyz[3 * p + 2],
                            __int_as_float(p));  // .w carries origidx (bitcast)
}

// ========================= ball query ==============================
__global__ __launch_bounds__(256) void k_ball(
    const float* __restrict__ xyz, const float4* __restrict__ rxyz,
    const int* __restrict__ kp, const int* __restrict__ cellcnt,
    const int* __restrict__ start, int* __restrict__ ids, int* __restrict__ nas,
    int* __restrict__ nbs, float* __restrict__ kx, float* __restrict__ ky,
    float* __restrict__ kz) {
#pragma clang fp contract(off)
    int k = blockIdx.x * 256 + threadIdx.x;
    if (k >= NKP) return;
    int kpi = kp[k];
    float qx = xyz[3 * kpi], qy = xyz[3 * kpi + 1], qz = xyz[3 * kpi + 2];
    kx[k] = qx; ky[k] = qy; kz[k] = qz;
    const float r2a = (float)(0.4 * 0.4);  // 1-ulp-exact vs python double->f32
    const float r2b = (float)(0.8 * 0.8);
    float d[16]; int id[16];
#pragma unroll
    for (int i = 0; i < 16; ++i) { d[i] = 3.0e38f; id[i] = 0x7fffffff; }
    int na = 0, nb = 0;
    int cx = min(max((int)qx, 0), GX - 1);
    int cy = min(max((int)qy, 0), GY - 1);
    int cz = min(max((int)qz, 0), GZ - 1);
    for (int zz = max(cz - 1, 0); zz <= min(cz + 1, GZ - 1); ++zz)
        for (int yy = max(cy - 1, 0); yy <= min(cy + 1, GY - 1); ++yy)
            for (int xx = max(cx - 1, 0); xx <= min(cx + 1, GX - 1); ++xx) {
                int c = (zz * GY + yy) * GX + xx;
                int s = start[c], e = s + cellcnt[c];
                for (int i = s; i < e; ++i) {
                    const float4 cc = rxyz[i];
                    float dx = cc.x - qx;
                    float dy = cc.y - qy;
                    float dzv = cc.z - qz;
                    float dd = dx * dx + dy * dy;
                    dd = dd + dzv * dzv;
                    if (dd <= r2b) {
                        int p = __float_as_int(cc.w);
                        nb++;
                        if (dd <= r2a) na++;
                        bool lt15 = (dd < d[15]) || (dd == d[15] && p < id[15]);
                        if (lt15) {
                            bool lt[16];
#pragma unroll
                            for (int j = 0; j < 16; ++j)
                                lt[j] = (dd < d[j]) || (dd == d[j] && p < id[j]);
#pragma unroll
                            for (int j = 15; j >= 1; --j) {
                                d[j] = lt[j - 1] ? d[j - 1] : (lt[j] ? dd : d[j]);
                                id[j] = lt[j - 1] ? id[j - 1] : (lt[j] ? p : id[j]);
                            }
                            if (lt[0]) { d[0] = dd; id[0] = p; }
                        }
                    }
                }
            }
    int na16 = min(na, 16), nb16 = min(nb, 16);
    nas[k] = na16;
    nbs[k] = nb16;
    int fill = (nb16 > 0) ? id[0] : 0;
#pragma unroll
    for (int s2 = 0; s2 < 16; ++s2) ids[k * 16 + s2] = (s2 < nb16) ? id[s2] : fill;
}

// ===================== grouped MLP + max pool ======================
__device__ __forceinline__ void sa_scale_eval(
    int n, const int* idk, int s, float qx, float qy, float qz,
    const float* __restrict__ xyz, const float* __restrict__ feats,
    const float* sW1, const float* sg1, const float* sb1, const float* sW2,
    const float* sg2, const float* sb2, float* h2out) {
    int pid = idk[(s < n) ? s : 0];
    float g0 = xyz[3 * pid + 0] - qx;
    float g1v = xyz[3 * pid + 1] - qy;
    float g2v = xyz[3 * pid + 2] - qz;
    float g3 = feats[2 * pid + 0];
    float g4 = feats[2 * pid + 1];
    float h1[16];
#pragma unroll
    for (int dd = 0; dd < 16; ++dd) {
        float acc = g0 * sW1[0 * 16 + dd];
        acc = acc + g1v * sW1[1 * 16 + dd];
        acc = acc + g2v * sW1[2 * 16 + dd];
        acc = acc + g3 * sW1[3 * 16 + dd];
        acc = acc + g4 * sW1[4 * 16 + dd];
        h1[dd] = fmaxf(acc * sg1[dd] + sb1[dd], 0.0f);
    }
#pragma unroll
    for (int dd = 0; dd < 16; ++dd) {
        float acc = h1[0] * sW2[0 * 16 + dd];
#pragma unroll
        for (int c = 1; c < 16; ++c) acc = acc + h1[c] * sW2[c * 16 + dd];
        float v = fmaxf(acc * sg2[dd] + sb2[dd], 0.0f);
#pragma unroll
        for (int off = 1; off < 16; off <<= 1) v = fmaxf(v, __shfl_xor(v, off));
        h2out[dd] = v;  // pooled over the 16-lane sample group
    }
}

__global__ __launch_bounds__(256) void k_mlp(
    const float* __restrict__ xyz, const float* __restrict__ feats,
    const int* __restrict__ ids, const int* __restrict__ nas, const int* __restrict__ nbs,
    const float* __restrict__ kx, const float* __restrict__ ky, const float* __restrict__ kz,
    const float* W1a, const float* g1a, const float* b1a, const float* W2a,
    const float* g2a, const float* b2a, const float* W1b, const float* g1b,
    const float* b1b, const float* W2b, const float* g2b, const float* b2b,
    float* __restrict__ pooled) {
#pragma clang fp contract(off)
    __shared__ float sW1a[80], sW2a[256], sg1a[16], sb1a[16], sg2a[16], sb2a[16];
    __shared__ float sW1b[80], sW2b[256], sg1b[16], sb1b[16], sg2b[16], sb2b[16];
    int t = threadIdx.x;
    if (t < 80) { sW1a[t] = W1a[t]; sW1b[t] = W1b[t]; }
    sW2a[t] = W2a[t];
    sW2b[t] = W2b[t];
    if (t < 16) {
        sg1a[t] = g1a[t]; sb1a[t] = b1a[t]; sg2a[t] = g2a[t]; sb2a[t] = b2a[t];
        sg1b[t] = g1b[t]; sb1b[t] = b1b[t]; sg2b[t] = g2b[t]; sb2b[t] = b2b[t];
    }
    __syncthreads();
    int wave = t >> 6, lane = t & 63;
    int kpl = lane >> 4, s = lane & 15;
    int k = blockIdx.x * 16 + wave * 4 + kpl;
    float qx = kx[k], qy = ky[k], qz = kz[k];
    int na = nas[k], nb = nbs[k];
    const int* idk = ids + k * 16;
    float h2a[16], h2b[16];
    sa_scale_eval(na, idk, s, qx, qy, qz, xyz, feats, sW1a, sg1a, sb1a, sW2a, sg2a, sb2a, h2a);
    sa_scale_eval(nb, idk, s, qx, qy, qz, xyz, feats, sW1b, sg1b, sb1b, sW2b, sg2b, sb2b, h2b);
    if (s == 0) {
#pragma unroll
        for (int dd = 0; dd < 16; ++dd) pooled[k * 32 + dd] = (na > 0) ? h2a[dd] : 0.0f;
#pragma unroll
        for (int dd = 0; dd < 16; ++dd) pooled[k * 32 + 16 + dd] = (nb > 0) ? h2b[dd] : 0.0f;
    }
}

// ================== FP: 3-NN interp + final MLP ====================
__global__ __launch_bounds__(256) void k_fp(
    const float* __restrict__ xyz, const float* __restrict__ kx,
    const float* __restrict__ ky, const float* __restrict__ kz,
    const float* __restrict__ pooled, const float* __restrict__ Wf,
    const float* __restrict__ gf, const float* __restrict__ bf,
    float* __restrict__ out) {
#pragma clang fp contract(off)
    __shared__ float skx[NKP], sky[NKP], skz[NKP];
    __shared__ float sWf[512], sgf[16], sbf[16];
    int t = threadIdx.x;
    for (int i = t; i < NKP; i += 256) { skx[i] = kx[i]; sky[i] = ky[i]; skz[i] = kz[i]; }
    for (int i = t; i < 512; i += 256) sWf[i] = Wf[i];
    if (t < 16) { sgf[t] = gf[t]; sbf[t] = bf[t]; }
    __syncthreads();
    int p = blockIdx.x * 256 + t;
    float x = xyz[3 * p], y = xyz[3 * p + 1], z = xyz[3 * p + 2];
    float dA = 3e38f, dB = 3e38f, dC = 3e38f;
    int iA = 0, iB = 0, iC = 0;
    for (int k = 0; k < NKP; ++k) {
        float dx = skx[k] - x;
        float dy = sky[k] - y;
        float dz = skz[k] - z;
        float dd = dx * dx + dy * dy;
        dd = dd + dz * dz;
        if (dd < dC) {            // strict < + ascending k == stable top_k ties
            if (dd < dB) {
                dC = dB; iC = iB;
                if (dd < dA) { dB = dA; iB = iA; dA = dd; iA = k; }
                else { dB = dd; iB = k; }
            } else { dC = dd; iC = k; }
        }
    }
    float s0 = __fsqrt_rn(fmaxf(dA, 1e-12f));
    float s1 = __fsqrt_rn(fmaxf(dB, 1e-12f));
    float s2 = __fsqrt_rn(fmaxf(dC, 1e-12f));
    float w0 = 1.0f / (s0 + 1e-8f);
    float w1 = 1.0f / (s1 + 1e-8f);
    float w2 = 1.0f / (s2 + 1e-8f);
    float wsum = (w0 + w1) + w2;
    w0 /= wsum; w1 /= wsum; w2 /= wsum;
    const float* P0 = pooled + iA * 32;
    const float* P1 = pooled + iB * 32;
    const float* P2 = pooled + iC * 32;
    float interp[32];
#pragma unroll
    for (int c = 0; c < 32; ++c) interp[c] = w0 * P0[c] + w1 * P1[c] + w2 * P2[c];
#pragma unroll
    for (int dd = 0; dd < 16; ++dd) {
        float acc = interp[0] * sWf[0 * 16 + dd];
#pragma unroll
        for (int c = 1; c < 32; ++c) acc = acc + interp[c] * sWf[c * 16 + dd];
        out[p * 16 + dd] = fmaxf(acc * sgf[dd] + sbf[dd], 0.0f);
    }
}

// ============================ launch ===============================
extern "C" void kernel_launch(void* const* d_in, const int* in_sizes, int n_in,
                              void* d_out, int out_size, void* d_ws, size_t ws_size,
                              hipStream_t stream) {
    const float* xyz = (const float*)d_in[0];
    const float* feats = (const float*)d_in[1];
    const float* Wf = (const float*)d_in[2];
    const float* gf = (const float*)d_in[3];
    const float* bf = (const float*)d_in[4];
    const float* W1a = (const float*)d_in[5];
    const float* g1a = (const float*)d_in[6];
    const float* b1a = (const float*)d_in[7];
    const float* W2a = (const float*)d_in[8];
    const float* g2a = (const float*)d_in[9];
    const float* b2a = (const float*)d_in[10];
    const float* W1b = (const float*)d_in[11];
    const float* g1b = (const float*)d_in[12];
    const float* b1b = (const float*)d_in[13];
    const float* W2b = (const float*)d_in[14];
    const float* g2b = (const float*)d_in[15];
    const float* b2b = (const float*)d_in[16];

    char* ws = (char*)d_ws;
    if (ws_size < 1835008) return;  // proven budget (rounds 3-11 passed)
    int* kp = (int*)(ws + 0);                // 16K
    int* cellcnt = (int*)(ws + 16384);       // 16K
    int* cellstart = (int*)(ws + 32768);     // 16K
    int* pcell = (int*)(ws + 49152);         // 128K
    int* prank = (int*)(ws + 180224);        // 128K
    float4* rxyz = (float4*)(ws + 442368);   // 512K (sorted order; .w = origidx)
    int* ids = (int*)(ws + 966656);          // 256K
    int* nas = (int*)(ws + 1228800);         // 16K
    int* nbs = (int*)(ws + 1245184);         // 16K
    float* kx = (float*)(ws + 1261568);      // 16K
    float* ky = (float*)(ws + 1277952);      // 16K
    float* kz = (float*)(ws + 1294336);      // 16K
    float* pooled = (float*)(ws + 1310720);  // 512K

    hipMemsetAsync(cellcnt, 0, NCELL_PAD * sizeof(int), stream);
    k_hist<<<NPT / 256, 256, 0, stream>>>(xyz, cellcnt, pcell, prank);
    k_scan<<<1, 1024, 0, stream>>>(cellcnt, cellstart);
    k_scatter<<<NPT / 256, 256, 0, stream>>>(xyz, pcell, prank, cellstart, rxyz);
    k_fps<<<1, FPS_T, 0, stream>>>(xyz, rxyz, kp);
    k_ball<<<NKP / 256, 256, 0, stream>>>(xyz, rxyz, kp, cellcnt, cellstart, ids, nas,
                                          nbs, kx, ky, kz);
    k_mlp<<<NKP / 16, 256, 0, stream>>>(xyz, feats, ids, nas, nbs, kx, ky, kz, W1a, g1a,
                                        b1a, W2a, g2a, b2a, W1b, g1b, b1b, W2b, g2b, b2b,
                                        pooled);
    k_fp<<<NPT / 256, 256, 0, stream>>>(xyz, kx, ky, kz, pooled, Wf, gf, bf, (float*)d_out);
}